// Round 1
// baseline (25.414 us; speedup 1.0000x reference)
//
#include <hip/hip_runtime.h>

#define BATCH 4096
#define INS   256
#define OUTS  256
#define NODES 128
#define NT    64      // output-column tile per workgroup
#define MCH   32      // sample rows per chunk (M tile)

typedef short short8 __attribute__((ext_vector_type(8)));
typedef float f32x4  __attribute__((ext_vector_type(4)));

struct SMem {
    unsigned short list[BATCH];   // sample ids for this expert
    int cnt;
};

__device__ __forceinline__ unsigned short f2bf(float f) {
    unsigned int u = __builtin_bit_cast(unsigned int, f);
    u += 0x7fffu + ((u >> 16) & 1u);   // round-to-nearest-even
    return (unsigned short)(u >> 16);
}

__device__ __forceinline__ short8 pack8(float4 a, float4 b) {
    short8 r;
    r[0] = (short)f2bf(a.x); r[1] = (short)f2bf(a.y);
    r[2] = (short)f2bf(a.z); r[3] = (short)f2bf(a.w);
    r[4] = (short)f2bf(b.x); r[5] = (short)f2bf(b.y);
    r[6] = (short)f2bf(b.z); r[7] = (short)f2bf(b.w);
    return r;
}

__global__ __launch_bounds__(256, 4) void moe_fwd(
    const float* __restrict__ x, const float* __restrict__ W1,
    const float* __restrict__ b1, const int* __restrict__ nid,
    float* __restrict__ out)
{
    __shared__ SMem sm;
    const int t   = threadIdx.x;
    const int bid = blockIdx.x;
    // XCD-chunked swizzle: all 4 column-quarters of an expert on one XCD.
    const int e  = (bid & 7) * 16 + ((bid >> 3) >> 2);
    const int c0 = ((bid >> 3) & 3) * NT;

    const int w  = t >> 6;     // wave 0..3 -> 16-col block
    const int l  = t & 63;
    const int g  = l >> 4;     // k-group
    const int ln = l & 15;
    const int cc = c0 + w * 16 + ln;

    if (t == 0) sm.cnt = 0;
    __syncthreads();           // nothing in flight yet; cheap full barrier

    // ---- issue W loads FIRST (direct to registers; each lane loads exactly
    // its own B-fragment elements). 64 scalar dword loads, coalesced 64B per
    // ln-group. These stream from HBM while the scan below runs on L2. ----
    const float* __restrict__ wp = W1 + (size_t)e * (INS * OUTS) + cc;
    float wraw[64];
    #pragma unroll
    for (int ks = 0; ks < 8; ++ks) {
        #pragma unroll
        for (int j = 0; j < 8; ++j)
            wraw[ks * 8 + j] = wp[(size_t)(ks * 32 + g * 8 + j) * OUTS];
    }
    const float bval = b1[e * OUTS + cc];

    // ---- scan node_ind[1]; bucket this expert's samples into LDS ----
    const int* __restrict__ idxp = nid + BATCH;
    #pragma unroll
    for (int it = 0; it < BATCH / 256; ++it) {
        int b = it * 256 + t;
        if (idxp[b] == e) {
            int p = atomicAdd(&sm.cnt, 1);
            sm.list[p] = (unsigned short)b;
        }
    }
    // Raw barrier: drain LDS (list/cnt visibility) but keep the W global
    // loads in flight across the barrier (no vmcnt drain).
    asm volatile("s_waitcnt lgkmcnt(0)" ::: "memory");
    __builtin_amdgcn_s_barrier();
    asm volatile("" ::: "memory");   // block hoisting LDS reads above barrier

    const int cnt = sm.cnt;
    if (cnt == 0) return;            // uniform across WG

    // ---- convert W to bf16 B-fragments (waits arrive per counted vmcnt) ----
    short8 wf[8];
    #pragma unroll
    for (int ks = 0; ks < 8; ++ks) {
        short8 v;
        #pragma unroll
        for (int j = 0; j < 8; ++j) v[j] = (short)f2bf(wraw[ks * 8 + j]);
        wf[ks] = v;
    }

    // ---- barrier-free chunk loop: x direct from global (L2-hot) ----
    for (int m0 = 0; m0 < cnt; m0 += MCH) {
        int r0 = m0 + ln;            // low A rows
        int r1 = m0 + 16 + ln;       // high A rows
        // clamp tail rows: garbage rows only feed discarded D rows
        int s0 = sm.list[r0 < cnt ? r0 : cnt - 1];
        int s1 = sm.list[r1 < cnt ? r1 : cnt - 1];
        const float* __restrict__ xp0 = x + (size_t)s0 * INS + g * 8;
        const float* __restrict__ xp1 = x + (size_t)s1 * INS + g * 8;

        f32x4 acc0 = {0.f, 0.f, 0.f, 0.f};
        f32x4 acc1 = {0.f, 0.f, 0.f, 0.f};
        #pragma unroll
        for (int ks = 0; ks < 8; ++ks) {
            float4 u0 = *reinterpret_cast<const float4*>(xp0 + ks * 32);
            float4 u1 = *reinterpret_cast<const float4*>(xp0 + ks * 32 + 4);
            float4 v0 = *reinterpret_cast<const float4*>(xp1 + ks * 32);
            float4 v1 = *reinterpret_cast<const float4*>(xp1 + ks * 32 + 4);
            short8 a0 = pack8(u0, u1);
            short8 a1 = pack8(v0, v1);
            acc0 = __builtin_amdgcn_mfma_f32_16x16x32_bf16(a0, wf[ks], acc0, 0, 0, 0);
            acc1 = __builtin_amdgcn_mfma_f32_16x16x32_bf16(a1, wf[ks], acc1, 0, 0, 0);
        }

        // ---- epilogue: D col = lane&15, row = (lane>>4)*4 + q ----
        #pragma unroll
        for (int q = 0; q < 4; ++q) {
            int rr0 = m0 + g * 4 + q;
            if (rr0 < cnt)
                out[(size_t)sm.list[rr0] * OUTS + cc] = acc0[q] + bval;
            int rr1 = m0 + 16 + g * 4 + q;
            if (rr1 < cnt)
                out[(size_t)sm.list[rr1] * OUTS + cc] = acc1[q] + bval;
        }
    }
}

extern "C" void kernel_launch(void* const* d_in, const int* in_sizes, int n_in,
                              void* d_out, int out_size, void* d_ws, size_t ws_size,
                              hipStream_t stream) {
    const float* x   = (const float*)d_in[0];
    // d_in[1] = var_vector (unused in forward)
    const float* W1  = (const float*)d_in[2];
    const float* b1  = (const float*)d_in[3];
    const int*   nid = (const int*)d_in[4];
    float* out = (float*)d_out;

    hipLaunchKernelGGL(moe_fwd, dim3(NODES * (OUTS / NT)), dim3(256), 0, stream,
                       x, W1, b1, nid, out);
}

// Round 3
// 24.376 us; speedup vs baseline: 1.0426x; 1.0426x over previous
//
#include <hip/hip_runtime.h>

#define BATCH 4096
#define INS   256
#define OUTS  256
#define NODES 128
#define NT    64      // output-column tile per workgroup
#define MCH   16      // sample rows per chunk (one 16-row MFMA tile)
#define MSPLIT 2      // m-split blocks per (expert, column-quarter)
#define MRANGE (BATCH / MSPLIT)   // sample-index range per m-split block

typedef short short8 __attribute__((ext_vector_type(8)));
typedef float f32x4  __attribute__((ext_vector_type(4)));

struct SMem {
    unsigned short list[MRANGE];  // sample ids (this block's index range only)
    int cnt;
};

__device__ __forceinline__ unsigned short f2bf(float f) {
    unsigned int u = __builtin_bit_cast(unsigned int, f);
    u += 0x7fffu + ((u >> 16) & 1u);   // round-to-nearest-even
    return (unsigned short)(u >> 16);
}

__device__ __forceinline__ short8 pack8(float4 a, float4 b) {
    short8 r;
    r[0] = (short)f2bf(a.x); r[1] = (short)f2bf(a.y);
    r[2] = (short)f2bf(a.z); r[3] = (short)f2bf(a.w);
    r[4] = (short)f2bf(b.x); r[5] = (short)f2bf(b.y);
    r[6] = (short)f2bf(b.z); r[7] = (short)f2bf(b.w);
    return r;
}

__global__ __launch_bounds__(256, 4) void moe_fwd(
    const float* __restrict__ x, const float* __restrict__ W1,
    const float* __restrict__ b1, const int* __restrict__ nid,
    float* __restrict__ out)
{
    __shared__ SMem sm;
    const int t   = threadIdx.x;
    const int bid = blockIdx.x;
    // XCD-chunked swizzle: all 8 blocks (4 col-quarters x 2 m-halves) of an
    // expert land on one XCD (same bid%8) for L2 reuse of W and x.
    const int sub = bid >> 3;              // 0..127 within XCD
    const int e   = (bid & 7) * 16 + (sub >> 3);
    const int c0  = ((sub >> 1) & 3) * NT;
    const int mh  = sub & 1;               // which sample-index half we own

    const int w  = t >> 6;     // wave 0..3 -> 16-col block
    const int l  = t & 63;
    const int g  = l >> 4;     // k-group
    const int ln = l & 15;
    const int cc = c0 + w * 16 + ln;

    if (t == 0) sm.cnt = 0;
    __syncthreads();           // nothing in flight yet; cheap full barrier

    // ---- issue W loads FIRST (direct to registers; each lane loads exactly
    // its own B-fragment elements), convert to bf16 immediately so only the
    // packed frags (32 VGPR) stay live. HBM latency overlaps the scan. ----
    const float* __restrict__ wp = W1 + (size_t)e * (INS * OUTS) + cc;
    short8 wf[8];
    #pragma unroll
    for (int ks = 0; ks < 8; ++ks) {
        short8 v;
        #pragma unroll
        for (int j = 0; j < 8; ++j)
            v[j] = (short)f2bf(wp[(size_t)(ks * 32 + g * 8 + j) * OUTS]);
        wf[ks] = v;
    }
    const float bval = b1[e * OUTS + cc];

    // ---- scan OUR index half of node_ind[1]; bucket matches. Ownership is
    // by sample index (deterministic), so no cross-block ordering races. ----
    const int* __restrict__ idxp = nid + BATCH + mh * MRANGE;
    #pragma unroll
    for (int it = 0; it < MRANGE / 256; ++it) {
        int b = it * 256 + t;
        if (idxp[b] == e) {
            int p = atomicAdd(&sm.cnt, 1);
            sm.list[p] = (unsigned short)(mh * MRANGE + b);
        }
    }
    // Raw barrier: drain LDS (list/cnt visibility) but keep W global loads
    // in flight across the barrier (no vmcnt drain).
    asm volatile("s_waitcnt lgkmcnt(0)" ::: "memory");
    __builtin_amdgcn_s_barrier();
    asm volatile("" ::: "memory");   // block hoisting LDS reads above barrier

    const int cnt = sm.cnt;
    if (cnt == 0) return;            // uniform across WG

    // ---- barrier-free chunk loop: 16 rows per chunk, x direct from L2 ----
    for (int m0 = 0; m0 < cnt; m0 += MCH) {
        int r0 = m0 + ln;
        // clamp tail rows: garbage rows only feed discarded D rows
        int s0 = sm.list[r0 < cnt ? r0 : cnt - 1];
        const float* __restrict__ xp0 = x + (size_t)s0 * INS + g * 8;

        f32x4 acc0 = {0.f, 0.f, 0.f, 0.f};
        #pragma unroll
        for (int ks = 0; ks < 8; ++ks) {
            float4 u0 = *reinterpret_cast<const float4*>(xp0 + ks * 32);
            float4 u1 = *reinterpret_cast<const float4*>(xp0 + ks * 32 + 4);
            short8 a0 = pack8(u0, u1);
            acc0 = __builtin_amdgcn_mfma_f32_16x16x32_bf16(a0, wf[ks], acc0, 0, 0, 0);
        }

        // ---- epilogue: D col = lane&15, row = (lane>>4)*4 + q ----
        #pragma unroll
        for (int q = 0; q < 4; ++q) {
            int rr = m0 + g * 4 + q;
            if (rr < cnt)
                out[(size_t)sm.list[rr] * OUTS + cc] = acc0[q] + bval;
        }
    }
}

extern "C" void kernel_launch(void* const* d_in, const int* in_sizes, int n_in,
                              void* d_out, int out_size, void* d_ws, size_t ws_size,
                              hipStream_t stream) {
    const float* x   = (const float*)d_in[0];
    // d_in[1] = var_vector (unused in forward)
    const float* W1  = (const float*)d_in[2];
    const float* b1  = (const float*)d_in[3];
    const int*   nid = (const int*)d_in[4];
    float* out = (float*)d_out;

    hipLaunchKernelGGL(moe_fwd, dim3(NODES * (OUTS / NT) * MSPLIT), dim3(256),
                       0, stream, x, W1, b1, nid, out);
}